// Round 2
// baseline (216.831 us; speedup 1.0000x reference)
//
#include <hip/hip_runtime.h>
#include <math.h>

// SplashEncoding: 16-level hash grid, trilinear interp; levels 14/15 add
// Gaussian splash mixtures (ns=2/4) feeding both feature and GMM outputs.
//
// R10 vs R9 (main 131.0us; VALU 16%, FETCH 113MB, 2.13 cyc/vmem-transaction):
//  - R9 post-mortem: fp8 tables cut FETCH 138->113MB but dur only -6% ->
//    NOT L3-traffic-bound. We sit at ~0.47 vmem transactions/cyc/CU with
//    every transaction an L1 miss => transaction/MSHR-throughput wall.
//  - Fix: cut transactions 144->112/pt by lane-coalescing the splash path.
//    Splash slots repacked PER-GAUSSIAN (16B quarter = {mo.xyz, i2s, inrm,
//    is2, f0, f1}); 4 (L15) / 2 (L14) adjacent lanes load the quarters of
//    the SAME slot in ONE instruction -> HW coalesces to 1 transaction/slot.
//    L15: 32->8 transactions/pt, L14: 16->8. Bonus: per-thread loads now go
//    to 4 independent random lines (better MLP than 1 miss + 3 dep hits).
//  - Existing shfl_xor reduction already sums all (corner,gaussian) partials.
//  - Kept from R9: fp8 e4m3 plain/linear tables (x16 pre-scale), L2-resident
//    3.2MB hot set. Kept from earlier: phase/cache separation, split-across-
//    threads work, precomputed reciprocals, full-line writes.

#define HMASK 131071
typedef float vf4 __attribute__((ext_vector_type(4)));
typedef float vf2 __attribute__((ext_vector_type(2)));
typedef _Float16 h8 __attribute__((ext_vector_type(8)));
typedef unsigned short u16;
typedef unsigned int u32;

// ws byte layout:
//   [0, 2621440)            : levels 4-13 fp8 tables (131072 entries x 2B each)
//   [2621440, 3343708)      : linear levels 0-3 fp8 PAIR table (entry idx ->
//                             {f[idx].xy, f[idx+1].xy} as 4 x fp8 = 1 dword)
//   [3670016, 7864320)      : L14 quarters (2 x 16B per slot)
//   [7864320, 16252928)     : L15 quarters (4 x 16B per slot)
#define LIN_OFF 2621440
#define L14_OFF 3670016
#define L15_OFF 7864320

// fbases (float2 rows) of hashed plain levels 4..13 (for repack + fallback)
__constant__ int c_fbh[10] = {180567,311639,442711,573783,704855,835927,
                              966999,1098071,1229143,1360215};
// pop0 per-q: linear levels 0..3, hashed levels 4..7
__constant__ int c_lres[4] = {16,23,34,50};
__constant__ int c_lfb[4]  = {0,4096,16263,55567};
__constant__ int c_h0res[4] = {74,109,161,237};
// pop1 per-q: levels 8+q and 11+q
__constant__ int c_p1resA[3] = {348,512,753};
__constant__ int c_p1resB[3] = {1108,1629,2394};

__device__ __forceinline__ void corner_setup(int res, float cx, float cy, float cz,
                                             int& px, int& py, int& pz,
                                             float& fx, float& fy, float& fz)
{
    const float hi = (float)res - 1.001f;            // matches jnp.clip(res*c, 0, res-1.001)
    float x = fminf(fmaxf((float)res * cx, 0.0f), hi);
    float y = fminf(fmaxf((float)res * cy, 0.0f), hi);
    float z = fminf(fmaxf((float)res * cz, 0.0f), hi);
    px = (int)x; py = (int)y; pz = (int)z;           // >=0 so trunc == floor
    fx = x - (float)px; fy = y - (float)py; fz = z - (float)pz;
}

// ---- fp32 fallback paths (workspace too small) --------------------------

__device__ __forceinline__ float2 linear_eval4(
    int res, int fbase, float cx, float cy, float cz,
    const float* __restrict__ feats)
{
    int px, py, pz; float fx, fy, fz;
    corner_setup(res, cx, cy, cz, px, py, pz, fx, fy, fz);
    int idxs[4]; float wyz[4];
#pragma unroll
    for (int j = 0; j < 4; ++j) {
        const int oy = (j >> 1) & 1, oz = j & 1;
        idxs[j] = px + (py + oy) * res + (pz + oz) * res * res;
        wyz[j] = (oy ? fy : 1.0f - fy) * (oz ? fz : 1.0f - fz);
    }
    vf4 fv[4];
#pragma unroll
    for (int j = 0; j < 4; ++j)
        fv[j] = *(const vf4*)(feats + (size_t)(fbase + idxs[j]) * 2);
    float a0 = 0.0f, a1 = 0.0f;
    const float gx = 1.0f - fx;
#pragma unroll
    for (int j = 0; j < 4; ++j) {
        a0 += wyz[j] * (gx * fv[j].x + fx * fv[j].z);
        a1 += wyz[j] * (gx * fv[j].y + fx * fv[j].w);
    }
    return make_float2(a0, a1);
}

__device__ __forceinline__ float2 plain_eval_f32h(
    int res, int fbase, float cx, float cy, float cz,
    const float* __restrict__ feats)
{
    int px, py, pz; float fx, fy, fz;
    corner_setup(res, cx, cy, cz, px, py, pz, fx, fy, fz);
    int   idxs[8];
    float ws[8];
#pragma unroll
    for (int k = 0; k < 8; ++k) {
        const int ox = (k >> 2) & 1, oy = (k >> 1) & 1, oz = k & 1;
        const int ix = px + ox, iy = py + oy, iz = pz + oz;
        ws[k] = (ox ? fx : 1.0f - fx) * (oy ? fy : 1.0f - fy) * (oz ? fz : 1.0f - fz);
        unsigned h = (unsigned)ix ^ ((unsigned)iy * 2654435761u) ^ ((unsigned)iz * 805459861u);
        idxs[k] = (int)(h & HMASK);
    }
    float2 fv[8];
#pragma unroll
    for (int k = 0; k < 8; ++k)
        fv[k] = *(const float2*)(feats + (size_t)(fbase + idxs[k]) * 2);
    float a0 = 0.0f, a1 = 0.0f;
#pragma unroll
    for (int k = 0; k < 8; ++k) { a0 += ws[k] * fv[k].x; a1 += ws[k] * fv[k].y; }
    return make_float2(a0, a1);
}

// ---- fp8 packed paths ----------------------------------------------------

// linear level, fp8 pair table: one dword load covers the ox=0/1 corner pair.
// Stored values are 16x; fold 1/16 into the return.
__device__ __forceinline__ float2 linear_eval4_fp8(
    int res, int ebase, float cx, float cy, float cz,
    const u32* __restrict__ ltab)
{
    int px, py, pz; float fx, fy, fz;
    corner_setup(res, cx, cy, cz, px, py, pz, fx, fy, fz);
    int idxs[4]; float wyz[4];
#pragma unroll
    for (int j = 0; j < 4; ++j) {
        const int oy = (j >> 1) & 1, oz = j & 1;
        idxs[j] = px + (py + oy) * res + (pz + oz) * res * res;
        wyz[j] = (oy ? fy : 1.0f - fy) * (oz ? fz : 1.0f - fz);
    }
    u32 u[4];
#pragma unroll
    for (int j = 0; j < 4; ++j) u[j] = ltab[ebase + idxs[j]];
    float a0 = 0.0f, a1 = 0.0f;
    const float gx = 1.0f - fx;
#pragma unroll
    for (int j = 0; j < 4; ++j) {
        vf2 lo = __builtin_amdgcn_cvt_pk_f32_fp8((int)u[j], false);  // ox=0
        vf2 hi = __builtin_amdgcn_cvt_pk_f32_fp8((int)u[j], true);   // ox=1
        a0 += wyz[j] * (gx * lo.x + fx * hi.x);
        a1 += wyz[j] * (gx * lo.y + fx * hi.y);
    }
    return make_float2(a0 * 0.0625f, a1 * 0.0625f);
}

// hashed plain level, fp8 table (2B/entry). Stored values are 16x.
__device__ __forceinline__ float2 plain_eval_fp8(
    int res, const u16* __restrict__ tab, float cx, float cy, float cz)
{
    int px, py, pz; float fx, fy, fz;
    corner_setup(res, cx, cy, cz, px, py, pz, fx, fy, fz);
    int   idxs[8];
    float ws[8];
#pragma unroll
    for (int k = 0; k < 8; ++k) {
        const int ox = (k >> 2) & 1, oy = (k >> 1) & 1, oz = k & 1;
        const int ix = px + ox, iy = py + oy, iz = pz + oz;
        ws[k] = (ox ? fx : 1.0f - fx) * (oy ? fy : 1.0f - fy) * (oz ? fz : 1.0f - fz);
        unsigned h = (unsigned)ix ^ ((unsigned)iy * 2654435761u) ^ ((unsigned)iz * 805459861u);
        idxs[k] = (int)(h & HMASK);
    }
    u16 v[8];
#pragma unroll
    for (int k = 0; k < 8; ++k) v[k] = tab[idxs[k]];
    float a0 = 0.0f, a1 = 0.0f;
#pragma unroll
    for (int k = 0; k < 8; ++k) {
        vf2 d = __builtin_amdgcn_cvt_pk_f32_fp8((int)v[k], false);
        a0 += ws[k] * d.x; a1 += ws[k] * d.y;
    }
    return make_float2(a0 * 0.0625f, a1 * 0.0625f);
}

// ---- splash (fp16 packed, per-gaussian quarters) -------------------------

__device__ __forceinline__ void gauss_pre(float w, float dx, float dy, float dz,
                                          float i2s, float inrm, float is2,
                                          float f0, float f1,
                                          float& a0, float& a1, float& ag)
{
    const float d2 = dx*dx + dy*dy + dz*dz;
    const float sq = d2 * i2s;
    const float gw = __expf(-sq) * inrm;
    const float wg = w * gw;
    a0 += wg * f0;
    a1 += wg * f1;
    ag += wg * (d2 * is2);
}

// Per-gaussian 16B quarter: {mx-.5, my-.5, mz-.5, i2s, inrm, is2, f0, f1}.
// Lane owns gaussian g of corners (ch + 2j), j=0..3. Adjacent lanes (same ch,
// g=0..NS-1) load consecutive quarters of the SAME slot in the same
// instruction -> HW coalesces into one transaction per slot.
template<int NS>
__device__ __forceinline__ void splash_quarters(
    int res, const h8* __restrict__ quart, int g, int ch,
    float cx, float cy, float cz, float cox, float coy, float coz,
    float& a0, float& a1, float& ag)
{
    int px, py, pz; float fx, fy, fz;
    corner_setup(res, cx, cy, cz, px, py, pz, fx, fy, fz);
    a0 = 0.0f; a1 = 0.0f; ag = 0.0f;
#pragma unroll
    for (int j = 0; j < 4; ++j) {
        const int k = ch + 2 * j;
        const int ox = (k >> 2) & 1, oy = (k >> 1) & 1, oz = k & 1;
        const int ix = px + ox, iy = py + oy, iz = pz + oz;
        const float w = (ox ? fx : 1.0f - fx) * (oy ? fy : 1.0f - fy) * (oz ? fz : 1.0f - fz);
        unsigned h = (unsigned)ix ^ ((unsigned)iy * 2654435761u) ^ ((unsigned)iz * 805459861u);
        const int idx = (int)(h & HMASK);
        h8 Q = quart[(size_t)idx * NS + g];
        gauss_pre(w, cox - (float)Q[0], coy - (float)Q[1], coz - (float)Q[2],
                  (float)Q[3], (float)Q[4], (float)Q[5], (float)Q[6], (float)Q[7],
                  a0, a1, ag);
    }
}

// fallback splash (direct fp32 table loads), corner range [k0, k0+KN)
template<int NS, int KN>
__device__ __forceinline__ void splash_direct_part(
    int k0, int res, int fbase, int gbase, float cx, float cy, float cz,
    const float* __restrict__ feats, const float* __restrict__ means,
    const float* __restrict__ stds, float& a0, float& a1, float& ag)
{
    int px, py, pz; float fx, fy, fz;
    corner_setup(res, cx, cy, cz, px, py, pz, fx, fy, fz);
    a0 = 0.0f; a1 = 0.0f; ag = 0.0f;
#pragma unroll
    for (int kk = 0; kk < KN; ++kk) {
        const int k = k0 + kk;
        const int ox = (k >> 2) & 1, oy = (k >> 1) & 1, oz = k & 1;
        const int ix = px + ox, iy = py + oy, iz = pz + oz;
        const float w = (ox ? fx : 1.0f - fx) * (oy ? fy : 1.0f - fy) * (oz ? fz : 1.0f - fz);
        unsigned h = (unsigned)ix ^ ((unsigned)iy * 2654435761u) ^ ((unsigned)iz * 805459861u);
        const int idx = (int)(h & HMASK);
        const int grow = gbase + idx * NS;
        const float* m = means + (size_t)grow * 3;
        const float* s = stds + grow;
        const float* f = feats + (size_t)(fbase + idx * NS) * 2;
#pragma unroll
        for (int si = 0; si < NS; ++si) {
            const float dx = cx - m[3*si], dy = cy - m[3*si+1], dz = cz - m[3*si+2];
            const float sva = fabsf(s[si]);
            const float d2 = dx*dx + dy*dy + dz*dz;
            const float s2 = sva * sva;
            const float sq = d2 / (2.0f * s2 + 1e-7f);
            const float gw = expf(-sq) / (2.5066282746310002f * sva + 1e-7f);
            const float wg = w * gw;
            a0 += wg * f[2*si];
            a1 += wg * f[2*si+1];
            ag += wg * (d2 / s2);
        }
    }
}

// repack threads (by block range):
//   [0,640)     plain levels 4-13 -> fp8, 8 entries/thread (16384 thr/level)
//   [640,1346)  linear pair table -> fp8, 1 entry/thread (180567 entries)
//   [1346,1858) L14 slots (131072) -> 2 per-gaussian quarters
//   [1858,2370) L15 slots (131072) -> 4 per-gaussian quarters
__global__ __launch_bounds__(256) void repack_kernel(
    const float* __restrict__ means, const float* __restrict__ stds,
    const float* __restrict__ feats, unsigned char* __restrict__ wsb)
{
    const int b = blockIdx.x;
    const int tid = threadIdx.x;
    if (b < 640) {
        const int j   = b * 256 + tid;      // 0..163839
        const int lvl = j >> 14;            // /16384
        const int e8  = (j & 16383) * 8;    // entry base, 8 entries/thread
        const float* src = feats + (size_t)(c_fbh[lvl] + e8) * 2;
        uint4 u;
        u32* up = (u32*)&u;
#pragma unroll
        for (int p = 0; p < 4; ++p) {       // 2 entries per dword
            vf4 f = *(const vf4*)(src + 4 * p);
            int w = __builtin_amdgcn_cvt_pk_fp8_f32(16.0f * f.x, 16.0f * f.y, 0, false);
            w = __builtin_amdgcn_cvt_pk_fp8_f32(16.0f * f.z, 16.0f * f.w, w, true);
            up[p] = (u32)w;
        }
        *(uint4*)(wsb + (size_t)lvl * 262144 + (size_t)e8 * 2) = u;   // 16B aligned
    } else if (b < 1346) {
        const int e = (b - 640) * 256 + tid;
        if (e < 180567) {
            // pair table: entry e holds {f[e].xy, f[e+1].xy}; f[e+1] read is
            // always in-bounds (feats continues into hashed-level rows).
            const float2 fa = *(const float2*)(feats + 2 * (size_t)e);
            const float2 fb = *(const float2*)(feats + 2 * (size_t)e + 2);
            int w = __builtin_amdgcn_cvt_pk_fp8_f32(16.0f * fa.x, 16.0f * fa.y, 0, false);
            w = __builtin_amdgcn_cvt_pk_fp8_f32(16.0f * fb.x, 16.0f * fb.y, w, true);
            ((u32*)(wsb + LIN_OFF))[e] = (u32)w;
        }
    } else if (b < 1858) {
        // level 14: ns=2, gbase=0, fbase=1491287
        // gaussian0 mean = (ma.x, ma.y, mb.x); gaussian1 = (mb.y, mc.x, mc.y)
        const int e = (b - 1346) * 256 + tid;
        const float2* m2 = (const float2*)(means + (size_t)e * 6);
        const float2 ma = m2[0], mb = m2[1], mc = m2[2];
        const float2 sv = *(const float2*)(stds + 2 * e);
        const float2* f2 = (const float2*)(feats + (size_t)(1491287 + 2 * e) * 2);
        const float2 fa = f2[0], fb = f2[1];
        const float s0 = fabsf(sv.x), s1 = fabsf(sv.y);
        h8 Q0, Q1;
        Q0[0] = (_Float16)(ma.x - 0.5f); Q0[1] = (_Float16)(ma.y - 0.5f); Q0[2] = (_Float16)(mb.x - 0.5f);
        Q0[3] = (_Float16)(1.0f / (2.0f * s0 * s0 + 1e-7f));
        Q0[4] = (_Float16)(1.0f / (2.5066282746310002f * s0 + 1e-7f));
        Q0[5] = (_Float16)(1.0f / (s0 * s0));
        Q0[6] = (_Float16)fa.x; Q0[7] = (_Float16)fa.y;
        Q1[0] = (_Float16)(mb.y - 0.5f); Q1[1] = (_Float16)(mc.x - 0.5f); Q1[2] = (_Float16)(mc.y - 0.5f);
        Q1[3] = (_Float16)(1.0f / (2.0f * s1 * s1 + 1e-7f));
        Q1[4] = (_Float16)(1.0f / (2.5066282746310002f * s1 + 1e-7f));
        Q1[5] = (_Float16)(1.0f / (s1 * s1));
        Q1[6] = (_Float16)fb.x; Q1[7] = (_Float16)fb.y;
        h8* dst = (h8*)(wsb + L14_OFF) + (size_t)e * 2;
        dst[0] = Q0; dst[1] = Q1;
    } else {
        // level 15: ns=4, gbase=262144, fbase=1753431
        // means: u=(m0x,m0y,m0z,m1x) v=(m1y,m1z,m2x,m2y) w=(m2z,m3x,m3y,m3z)
        const int e = (b - 1858) * 256 + tid;
        const vf4* m4 = (const vf4*)(means + (size_t)(262144 + 4 * e) * 3);
        const vf4 u = m4[0], v = m4[1], w = m4[2];
        const vf4 s4 = *(const vf4*)(stds + 262144 + 4 * e);
        const float2* f2 = (const float2*)(feats + (size_t)(1753431 + 4 * e) * 2);
        const float2 fv[4] = {f2[0], f2[1], f2[2], f2[3]};
        const float mx[4] = {u.x, u.w, v.z, w.y};
        const float my[4] = {u.y, v.x, v.w, w.z};
        const float mz[4] = {u.z, v.y, w.x, w.w};
        const float sv[4] = {fabsf(s4.x), fabsf(s4.y), fabsf(s4.z), fabsf(s4.w)};
        h8* dst = (h8*)(wsb + L15_OFF) + (size_t)e * 4;
#pragma unroll
        for (int g = 0; g < 4; ++g) {
            h8 Q;
            Q[0] = (_Float16)(mx[g] - 0.5f);
            Q[1] = (_Float16)(my[g] - 0.5f);
            Q[2] = (_Float16)(mz[g] - 0.5f);
            Q[3] = (_Float16)(1.0f / (2.0f * sv[g] * sv[g] + 1e-7f));
            Q[4] = (_Float16)(1.0f / (2.5066282746310002f * sv[g] + 1e-7f));
            Q[5] = (_Float16)(1.0f / (sv[g] * sv[g]));
            Q[6] = (_Float16)fv[g].x; Q[7] = (_Float16)fv[g].y;
            dst[g] = Q;
        }
    }
}

// grid: [0,4096) pop0 lv0-7 4thr/pt | [4096,7168) pop1 lv8-13 3thr/pt |
//       [7168,11264) L14 4thr/pt | [11264,19456) L15 8thr/pt
template<bool PACKED>
__global__ __launch_bounds__(256) void splash_enc(
    const float* __restrict__ coords, const float* __restrict__ feats,
    const float* __restrict__ means,  const float* __restrict__ stds,
    const unsigned char* __restrict__ wsb, float* __restrict__ out, int N)
{
    const int b = blockIdx.x;
    const int tid = threadIdx.x;
    const u16* ptab = (const u16*)wsb;                 // plain fp8: level L in [4,13] -> + (L-4)*131072
    const u32* ltab = (const u32*)(wsb + LIN_OFF);     // linear fp8 pair table
    float* gmm = out + (size_t)N * 32;

    if (b < 4096) {
        // ---- pop0: levels 0-7, thread q: linear level q + hashed level q+4
        const int t = b * 256 + tid;
        const int n = t >> 2, q = t & 3;
        const float cx = coords[3*n+0], cy = coords[3*n+1], cz = coords[3*n+2];
        float2 rlin, rhsh;
        if (PACKED) {
            rlin = linear_eval4_fp8(c_lres[q], c_lfb[q], cx, cy, cz, ltab);
            rhsh = plain_eval_fp8(c_h0res[q], ptab + q * 131072, cx, cy, cz);
        } else {
            rlin = linear_eval4(c_lres[q], c_lfb[q], cx, cy, cz, feats);
            rhsh = plain_eval_f32h(c_h0res[q], c_fbh[q], cx, cy, cz, feats);
        }
        *(float2*)(out + (size_t)n * 32 + 2 * q)     = rlin;
        *(float2*)(out + (size_t)n * 32 + 8 + 2 * q) = rhsh;
    } else if (b < 7168) {
        // ---- pop1: levels 8-13, thread q: levels 8+q and 11+q
        const int t = (b - 4096) * 256 + tid;               // [0, 786432)
        const int n = (int)(((unsigned long long)(unsigned)t * 0xAAAAAAABull) >> 33);
        const int q = t - 3 * n;
        const float cx = coords[3*n+0], cy = coords[3*n+1], cz = coords[3*n+2];
        float2 rA, rB;
        if (PACKED) {
            rA = plain_eval_fp8(c_p1resA[q], ptab + (4 + q) * 131072, cx, cy, cz);
            rB = plain_eval_fp8(c_p1resB[q], ptab + (7 + q) * 131072, cx, cy, cz);
        } else {
            rA = plain_eval_f32h(c_p1resA[q], c_fbh[4 + q], cx, cy, cz, feats);
            rB = plain_eval_f32h(c_p1resB[q], c_fbh[7 + q], cx, cy, cz, feats);
        }
        *(float2*)(out + (size_t)n * 32 + 16 + 2 * q) = rA;
        *(float2*)(out + (size_t)n * 32 + 22 + 2 * q) = rB;
    } else if (b < 11264) {
        // ---- L14: 4 threads/point; lane = gaussian (q&1) of corners (q>>1)+2j
        const int t = (b - 7168) * 256 + tid;
        const int n = t >> 2, q = t & 3;
        const float cx = coords[3*n+0], cy = coords[3*n+1], cz = coords[3*n+2];
        float a0, a1, ag;
        if (PACKED) {
            splash_quarters<2>(3520, (const h8*)(wsb + L14_OFF), q & 1, q >> 1,
                               cx, cy, cz, cx - 0.5f, cy - 0.5f, cz - 0.5f, a0, a1, ag);
        } else {
            splash_direct_part<2,2>(q * 2, 3520, 1491287, 0, cx, cy, cz,
                                    feats, means, stds, a0, a1, ag);
        }
        a0 += __shfl_xor(a0, 1); a1 += __shfl_xor(a1, 1); ag += __shfl_xor(ag, 1);
        a0 += __shfl_xor(a0, 2); a1 += __shfl_xor(a1, 2); ag += __shfl_xor(ag, 2);
        if (q == 0) {
            *(float2*)(out + (size_t)n * 32 + 28) = make_float2(a0, a1);
            gmm[2 * n] = ag;
        }
    } else {
        // ---- L15: 8 threads/point; lane = gaussian (q&3) of corners (q>>2)+2j
        const int t = (b - 11264) * 256 + tid;
        const int n = t >> 3, q = t & 7;
        const float cx = coords[3*n+0], cy = coords[3*n+1], cz = coords[3*n+2];
        float a0, a1, ag;
        if (PACKED) {
            splash_quarters<4>(5174, (const h8*)(wsb + L15_OFF), q & 3, q >> 2,
                               cx, cy, cz, cx - 0.5f, cy - 0.5f, cz - 0.5f, a0, a1, ag);
        } else {
            splash_direct_part<4,1>(q, 5174, 1753431, 262144, cx, cy, cz,
                                    feats, means, stds, a0, a1, ag);
        }
        a0 += __shfl_xor(a0, 1); a1 += __shfl_xor(a1, 1); ag += __shfl_xor(ag, 1);
        a0 += __shfl_xor(a0, 2); a1 += __shfl_xor(a1, 2); ag += __shfl_xor(ag, 2);
        a0 += __shfl_xor(a0, 4); a1 += __shfl_xor(a1, 4); ag += __shfl_xor(ag, 4);
        if (q == 0) {
            *(float2*)(out + (size_t)n * 32 + 30) = make_float2(a0, a1);
            gmm[2 * n + 1] = ag;
        }
    }
}

extern "C" void kernel_launch(void* const* d_in, const int* in_sizes, int n_in,
                              void* d_out, int out_size, void* d_ws, size_t ws_size,
                              hipStream_t stream) {
    const float* coords = (const float*)d_in[0];
    const float* feats  = (const float*)d_in[1];
    const float* means  = (const float*)d_in[2];
    const float* stds   = (const float*)d_in[3];
    float* out = (float*)d_out;
    const int N = in_sizes[0] / 3;   // 262144

    const bool packed = (ws_size >= 17825792);   // need 15.5MB; keep old gate
    if (packed) {
        repack_kernel<<<2370, 256, 0, stream>>>(means, stds, feats, (unsigned char*)d_ws);
        splash_enc<true><<<19456, 256, 0, stream>>>(coords, feats, means, stds,
                                                    (const unsigned char*)d_ws, out, N);
    } else {
        splash_enc<false><<<19456, 256, 0, stream>>>(coords, feats, means, stds,
                                                     (const unsigned char*)d_ws, out, N);
    }
}

// Round 3
// 208.414 us; speedup vs baseline: 1.0404x; 1.0404x over previous
//
#include <hip/hip_runtime.h>
#include <math.h>

// SplashEncoding: 16-level hash grid, trilinear interp; levels 14/15 add
// Gaussian splash mixtures (ns=2/4) feeding both feature and GMM outputs.
//
// R11 vs R10 (main 132.5us): lane-load reduction probe. R8/R9/R10 showed dur
// invariant to txns (R10: -22% -> 0), bytes+latency (R9: -50% bytes, L3->L2
// -> only -6%). The invariant across all three: 144 per-lane loads/pt at
// ~2.13 cyc each. This round: 144 -> 128 lane-loads/pt, requests ~flat:
//  - linear levels 0-3: injective index (NO hash) -> entry can exactly hold
//    all 4 xy-corner pairs (8 fp8 = 8B). 4 loads -> 2 loads (z, z+1). EXACT.
//  - L15: 48B SoA slots (drop inrm/is2, derived from i2s: is2=2*i2s,
//    inrm=sqrt(i2s/pi), rel err ~3e-6). 3 chunks x 16B; quad lanes g=0..2
//    load one chunk each, redistribute via __shfl (idle DS pipe).
//    32 -> 24 lane-loads/pt; L15 table 8MB -> 6MB.
// If neutral: L2 random-request rate is the binding resource (hash precludes
// corner merging; sort yields <6% net at 0.65 pts/voxel density) -> roofline.

#define HMASK 131071
typedef float vf4 __attribute__((ext_vector_type(4)));
typedef float vf2 __attribute__((ext_vector_type(2)));
typedef _Float16 h8 __attribute__((ext_vector_type(8)));
typedef _Float16 h2 __attribute__((ext_vector_type(2)));
typedef unsigned short u16;
typedef unsigned int u32;

// ws byte layout:
//   [0, 2621440)            : levels 4-13 fp8 tables (131072 x 2B)
//   [2621440, 4065976)      : linear levels 0-3 merged-xy fp8 (180567 x 8B)
//   [4194304, 8388608)      : L14 quarters (2 x 16B per slot)
//   [8388608, 14680064)     : L15 SoA slots (3 x 16B = 48B per slot)
#define LIN_OFF 2621440
#define L14_OFF 4194304
#define L15_OFF 8388608

// fbases (float2 rows) of hashed plain levels 4..13 (for repack + fallback)
__constant__ int c_fbh[10] = {180567,311639,442711,573783,704855,835927,
                              966999,1098071,1229143,1360215};
// pop0 per-q: linear levels 0..3, hashed levels 4..7
__constant__ int c_lres[4] = {16,23,34,50};
__constant__ int c_lfb[4]  = {0,4096,16263,55567};
__constant__ int c_h0res[4] = {74,109,161,237};
// pop1 per-q: levels 8+q and 11+q
__constant__ int c_p1resA[3] = {348,512,753};
__constant__ int c_p1resB[3] = {1108,1629,2394};

__device__ __forceinline__ void corner_setup(int res, float cx, float cy, float cz,
                                             int& px, int& py, int& pz,
                                             float& fx, float& fy, float& fz)
{
    const float hi = (float)res - 1.001f;            // matches jnp.clip(res*c, 0, res-1.001)
    float x = fminf(fmaxf((float)res * cx, 0.0f), hi);
    float y = fminf(fmaxf((float)res * cy, 0.0f), hi);
    float z = fminf(fmaxf((float)res * cz, 0.0f), hi);
    px = (int)x; py = (int)y; pz = (int)z;           // >=0 so trunc == floor
    fx = x - (float)px; fy = y - (float)py; fz = z - (float)pz;
}

__device__ __forceinline__ float hsel_f(u32 w, int sel) {
    h2 v;
    __builtin_memcpy(&v, &w, 4);
    return (float)v[sel];
}

// ---- fp32 fallback paths (workspace too small) --------------------------

__device__ __forceinline__ float2 linear_eval4(
    int res, int fbase, float cx, float cy, float cz,
    const float* __restrict__ feats)
{
    int px, py, pz; float fx, fy, fz;
    corner_setup(res, cx, cy, cz, px, py, pz, fx, fy, fz);
    int idxs[4]; float wyz[4];
#pragma unroll
    for (int j = 0; j < 4; ++j) {
        const int oy = (j >> 1) & 1, oz = j & 1;
        idxs[j] = px + (py + oy) * res + (pz + oz) * res * res;
        wyz[j] = (oy ? fy : 1.0f - fy) * (oz ? fz : 1.0f - fz);
    }
    vf4 fv[4];
#pragma unroll
    for (int j = 0; j < 4; ++j)
        fv[j] = *(const vf4*)(feats + (size_t)(fbase + idxs[j]) * 2);
    float a0 = 0.0f, a1 = 0.0f;
    const float gx = 1.0f - fx;
#pragma unroll
    for (int j = 0; j < 4; ++j) {
        a0 += wyz[j] * (gx * fv[j].x + fx * fv[j].z);
        a1 += wyz[j] * (gx * fv[j].y + fx * fv[j].w);
    }
    return make_float2(a0, a1);
}

__device__ __forceinline__ float2 plain_eval_f32h(
    int res, int fbase, float cx, float cy, float cz,
    const float* __restrict__ feats)
{
    int px, py, pz; float fx, fy, fz;
    corner_setup(res, cx, cy, cz, px, py, pz, fx, fy, fz);
    int   idxs[8];
    float ws[8];
#pragma unroll
    for (int k = 0; k < 8; ++k) {
        const int ox = (k >> 2) & 1, oy = (k >> 1) & 1, oz = k & 1;
        const int ix = px + ox, iy = py + oy, iz = pz + oz;
        ws[k] = (ox ? fx : 1.0f - fx) * (oy ? fy : 1.0f - fy) * (oz ? fz : 1.0f - fz);
        unsigned h = (unsigned)ix ^ ((unsigned)iy * 2654435761u) ^ ((unsigned)iz * 805459861u);
        idxs[k] = (int)(h & HMASK);
    }
    float2 fv[8];
#pragma unroll
    for (int k = 0; k < 8; ++k)
        fv[k] = *(const float2*)(feats + (size_t)(fbase + idxs[k]) * 2);
    float a0 = 0.0f, a1 = 0.0f;
#pragma unroll
    for (int k = 0; k < 8; ++k) { a0 += ws[k] * fv[k].x; a1 += ws[k] * fv[k].y; }
    return make_float2(a0, a1);
}

// ---- fp8 packed paths ----------------------------------------------------

// linear level, merged-xy fp8 table: entry (px,py,pz) holds the 4 xy-corner
// feature pairs {c00,c10,c01,c11} as 8 fp8. Index is injective (no hash),
// so this is EXACT. Two loads: z and z+1. Values 16x; fold 1/16 at the end.
__device__ __forceinline__ float2 linear_eval2_fp8(
    int res, int ebase, float cx, float cy, float cz,
    const unsigned char* __restrict__ wsb)
{
    int px, py, pz; float fx, fy, fz;
    corner_setup(res, cx, cy, cz, px, py, pz, fx, fy, fz);
    const int r2 = res * res;
    const int i0 = ebase + px + py * res + pz * r2;
    const uint2 u0 = *(const uint2*)(wsb + LIN_OFF + (size_t)i0 * 8);
    const uint2 u1 = *(const uint2*)(wsb + LIN_OFF + (size_t)(i0 + r2) * 8);
    const float wx0 = 1.0f - fx, wy0 = 1.0f - fy;
    float a0, a1;
    {
        vf2 c00 = __builtin_amdgcn_cvt_pk_f32_fp8((int)u0.x, false);
        vf2 c10 = __builtin_amdgcn_cvt_pk_f32_fp8((int)u0.x, true);
        vf2 c01 = __builtin_amdgcn_cvt_pk_f32_fp8((int)u0.y, false);
        vf2 c11 = __builtin_amdgcn_cvt_pk_f32_fp8((int)u0.y, true);
        vf2 d00 = __builtin_amdgcn_cvt_pk_f32_fp8((int)u1.x, false);
        vf2 d10 = __builtin_amdgcn_cvt_pk_f32_fp8((int)u1.x, true);
        vf2 d01 = __builtin_amdgcn_cvt_pk_f32_fp8((int)u1.y, false);
        vf2 d11 = __builtin_amdgcn_cvt_pk_f32_fp8((int)u1.y, true);
        vf2 s0, s1;
        s0.x = wy0 * (wx0 * c00.x + fx * c10.x) + fy * (wx0 * c01.x + fx * c11.x);
        s0.y = wy0 * (wx0 * c00.y + fx * c10.y) + fy * (wx0 * c01.y + fx * c11.y);
        s1.x = wy0 * (wx0 * d00.x + fx * d10.x) + fy * (wx0 * d01.x + fx * d11.x);
        s1.y = wy0 * (wx0 * d00.y + fx * d10.y) + fy * (wx0 * d01.y + fx * d11.y);
        a0 = (1.0f - fz) * s0.x + fz * s1.x;
        a1 = (1.0f - fz) * s0.y + fz * s1.y;
    }
    return make_float2(a0 * 0.0625f, a1 * 0.0625f);
}

// hashed plain level, fp8 table (2B/entry). Stored values are 16x.
__device__ __forceinline__ float2 plain_eval_fp8(
    int res, const u16* __restrict__ tab, float cx, float cy, float cz)
{
    int px, py, pz; float fx, fy, fz;
    corner_setup(res, cx, cy, cz, px, py, pz, fx, fy, fz);
    int   idxs[8];
    float ws[8];
#pragma unroll
    for (int k = 0; k < 8; ++k) {
        const int ox = (k >> 2) & 1, oy = (k >> 1) & 1, oz = k & 1;
        const int ix = px + ox, iy = py + oy, iz = pz + oz;
        ws[k] = (ox ? fx : 1.0f - fx) * (oy ? fy : 1.0f - fy) * (oz ? fz : 1.0f - fz);
        unsigned h = (unsigned)ix ^ ((unsigned)iy * 2654435761u) ^ ((unsigned)iz * 805459861u);
        idxs[k] = (int)(h & HMASK);
    }
    u16 v[8];
#pragma unroll
    for (int k = 0; k < 8; ++k) v[k] = tab[idxs[k]];
    float a0 = 0.0f, a1 = 0.0f;
#pragma unroll
    for (int k = 0; k < 8; ++k) {
        vf2 d = __builtin_amdgcn_cvt_pk_f32_fp8((int)v[k], false);
        a0 += ws[k] * d.x; a1 += ws[k] * d.y;
    }
    return make_float2(a0 * 0.0625f, a1 * 0.0625f);
}

// ---- splash (fp16 packed) ------------------------------------------------

__device__ __forceinline__ void gauss_pre(float w, float dx, float dy, float dz,
                                          float i2s, float inrm, float is2,
                                          float f0, float f1,
                                          float& a0, float& a1, float& ag)
{
    const float d2 = dx*dx + dy*dy + dz*dz;
    const float sq = d2 * i2s;
    const float gw = __expf(-sq) * inrm;
    const float wg = w * gw;
    a0 += wg * f0;
    a1 += wg * f1;
    ag += wg * (d2 * is2);
}

// L14: per-gaussian 16B quarter {mx-.5, my-.5, mz-.5, i2s, inrm, is2, f0, f1}.
// Lane owns gaussian g of corners (ch + 2j); adjacent lanes coalesce.
__device__ __forceinline__ void splash14_quarters(
    const h8* __restrict__ quart, int g, int ch,
    float cx, float cy, float cz, float cox, float coy, float coz,
    float& a0, float& a1, float& ag)
{
    int px, py, pz; float fx, fy, fz;
    corner_setup(3520, cx, cy, cz, px, py, pz, fx, fy, fz);
    a0 = 0.0f; a1 = 0.0f; ag = 0.0f;
#pragma unroll
    for (int j = 0; j < 4; ++j) {
        const int k = ch + 2 * j;
        const int ox = (k >> 2) & 1, oy = (k >> 1) & 1, oz = k & 1;
        const int ix = px + ox, iy = py + oy, iz = pz + oz;
        const float w = (ox ? fx : 1.0f - fx) * (oy ? fy : 1.0f - fy) * (oz ? fz : 1.0f - fz);
        unsigned h = (unsigned)ix ^ ((unsigned)iy * 2654435761u) ^ ((unsigned)iz * 805459861u);
        const int idx = (int)(h & HMASK);
        h8 Q = quart[(size_t)idx * 2 + g];
        gauss_pre(w, cox - (float)Q[0], coy - (float)Q[1], coz - (float)Q[2],
                  (float)Q[3], (float)Q[4], (float)Q[5], (float)Q[6], (float)Q[7],
                  a0, a1, ag);
    }
}

// L15: 48B SoA slot = chunk0 {mx[0..3],my[0..3]}, chunk1 {mz[0..3],i2s[0..3]},
// chunk2 {f0[0..3],f1[0..3]}. Quad lanes g=0..2 load chunk g (lane 3 loads
// nothing); redistribution via __shfl on the DS pipe. inrm/is2 derived from
// i2s (is2 = 2*i2s, inrm = sqrt(i2s/pi); rel err ~3e-6 vs stored).
__device__ __forceinline__ void splash15_soa(
    int lane, float cx, float cy, float cz, float cox, float coy, float coz,
    const unsigned char* __restrict__ wsb, float& a0, float& a1, float& ag)
{
    int px, py, pz; float fx, fy, fz;
    corner_setup(5174, cx, cy, cz, px, py, pz, fx, fy, fz);
    a0 = 0.0f; a1 = 0.0f; ag = 0.0f;
    const int q  = lane & 7;
    const int ch = q >> 2, g = q & 3;
    const int B  = lane & ~3;
    const int hdw = g >> 1;     // which dword of the half-pair
    const int hsel = g & 1;     // which half within the dword
#pragma unroll
    for (int j = 0; j < 4; ++j) {
        const int k = ch + 2 * j;
        const int ox = (k >> 2) & 1, oy = (k >> 1) & 1, oz = k & 1;
        const int ix = px + ox, iy = py + oy, iz = pz + oz;
        const float w = (ox ? fx : 1.0f - fx) * (oy ? fy : 1.0f - fy) * (oz ? fz : 1.0f - fz);
        unsigned h = (unsigned)ix ^ ((unsigned)iy * 2654435761u) ^ ((unsigned)iz * 805459861u);
        const int idx = (int)(h & HMASK);
        uint4 ck = make_uint4(0u, 0u, 0u, 0u);
        if (g < 3)
            ck = *(const uint4*)(wsb + L15_OFF + (size_t)idx * 48 + (size_t)g * 16);
        // pull all 4 dwords of each source lane's chunk
        const u32 x01 = (u32)__shfl((int)ck.x, B,     64);
        const u32 x23 = (u32)__shfl((int)ck.y, B,     64);
        const u32 y01 = (u32)__shfl((int)ck.z, B,     64);
        const u32 y23 = (u32)__shfl((int)ck.w, B,     64);
        const u32 z01 = (u32)__shfl((int)ck.x, B + 1, 64);
        const u32 z23 = (u32)__shfl((int)ck.y, B + 1, 64);
        const u32 s01 = (u32)__shfl((int)ck.z, B + 1, 64);
        const u32 s23 = (u32)__shfl((int)ck.w, B + 1, 64);
        const u32 f001 = (u32)__shfl((int)ck.x, B + 2, 64);
        const u32 f023 = (u32)__shfl((int)ck.y, B + 2, 64);
        const u32 f101 = (u32)__shfl((int)ck.z, B + 2, 64);
        const u32 f123 = (u32)__shfl((int)ck.w, B + 2, 64);
        const float mx  = hsel_f(hdw ? x23 : x01, hsel);
        const float my  = hsel_f(hdw ? y23 : y01, hsel);
        const float mz  = hsel_f(hdw ? z23 : z01, hsel);
        const float i2s = hsel_f(hdw ? s23 : s01, hsel);
        const float f0  = hsel_f(hdw ? f023 : f001, hsel);
        const float f1  = hsel_f(hdw ? f123 : f101, hsel);
        const float inrm = __fsqrt_rn(i2s * 0.31830988618f);   // sqrt(i2s/pi)
        const float is2  = 2.0f * i2s;
        gauss_pre(w, cox - mx, coy - my, coz - mz, i2s, inrm, is2, f0, f1, a0, a1, ag);
    }
}

// fallback splash (direct fp32 table loads), corner range [k0, k0+KN)
template<int NS, int KN>
__device__ __forceinline__ void splash_direct_part(
    int k0, int res, int fbase, int gbase, float cx, float cy, float cz,
    const float* __restrict__ feats, const float* __restrict__ means,
    const float* __restrict__ stds, float& a0, float& a1, float& ag)
{
    int px, py, pz; float fx, fy, fz;
    corner_setup(res, cx, cy, cz, px, py, pz, fx, fy, fz);
    a0 = 0.0f; a1 = 0.0f; ag = 0.0f;
#pragma unroll
    for (int kk = 0; kk < KN; ++kk) {
        const int k = k0 + kk;
        const int ox = (k >> 2) & 1, oy = (k >> 1) & 1, oz = k & 1;
        const int ix = px + ox, iy = py + oy, iz = pz + oz;
        const float w = (ox ? fx : 1.0f - fx) * (oy ? fy : 1.0f - fy) * (oz ? fz : 1.0f - fz);
        unsigned h = (unsigned)ix ^ ((unsigned)iy * 2654435761u) ^ ((unsigned)iz * 805459861u);
        const int idx = (int)(h & HMASK);
        const int grow = gbase + idx * NS;
        const float* m = means + (size_t)grow * 3;
        const float* s = stds + grow;
        const float* f = feats + (size_t)(fbase + idx * NS) * 2;
#pragma unroll
        for (int si = 0; si < NS; ++si) {
            const float dx = cx - m[3*si], dy = cy - m[3*si+1], dz = cz - m[3*si+2];
            const float sva = fabsf(s[si]);
            const float d2 = dx*dx + dy*dy + dz*dz;
            const float s2 = sva * sva;
            const float sq = d2 / (2.0f * s2 + 1e-7f);
            const float gw = expf(-sq) / (2.5066282746310002f * sva + 1e-7f);
            const float wg = w * gw;
            a0 += wg * f[2*si];
            a1 += wg * f[2*si+1];
            ag += wg * (d2 / s2);
        }
    }
}

// ---- repack --------------------------------------------------------------

template<int RES>
__device__ __forceinline__ void pack_lin_xy(
    int e, int lfb, const float* __restrict__ feats, unsigned char* __restrict__ wsb)
{
    const int local = e - lfb;
    const int px = local % RES;
    const int t  = local / RES;
    const int py = t % RES;
    // partners clamped at grid edge (never queried there; keeps reads in-region)
    const int dx = (px + 1 < RES) ? 1 : 0;
    const int dy = (py + 1 < RES) ? RES : 0;
    const float2 f00 = *(const float2*)(feats + 2 * (size_t)e);
    const float2 f10 = *(const float2*)(feats + 2 * (size_t)(e + dx));
    const float2 f01 = *(const float2*)(feats + 2 * (size_t)(e + dy));
    const float2 f11 = *(const float2*)(feats + 2 * (size_t)(e + dx + dy));
    int w0 = __builtin_amdgcn_cvt_pk_fp8_f32(16.0f * f00.x, 16.0f * f00.y, 0, false);
    w0 = __builtin_amdgcn_cvt_pk_fp8_f32(16.0f * f10.x, 16.0f * f10.y, w0, true);
    int w1 = __builtin_amdgcn_cvt_pk_fp8_f32(16.0f * f01.x, 16.0f * f01.y, 0, false);
    w1 = __builtin_amdgcn_cvt_pk_fp8_f32(16.0f * f11.x, 16.0f * f11.y, w1, true);
    *(uint2*)(wsb + LIN_OFF + (size_t)e * 8) = make_uint2((u32)w0, (u32)w1);
}

// repack threads (by block range):
//   [0,640)     plain levels 4-13 -> fp8, 8 entries/thread
//   [640,1346)  linear merged-xy table, 1 entry/thread (180567 entries)
//   [1346,1858) L14 slots (131072) -> 2 per-gaussian quarters
//   [1858,2370) L15 slots (131072) -> 3-chunk SoA (48B)
__global__ __launch_bounds__(256) void repack_kernel(
    const float* __restrict__ means, const float* __restrict__ stds,
    const float* __restrict__ feats, unsigned char* __restrict__ wsb)
{
    const int b = blockIdx.x;
    const int tid = threadIdx.x;
    if (b < 640) {
        const int j   = b * 256 + tid;      // 0..163839
        const int lvl = j >> 14;            // /16384
        const int e8  = (j & 16383) * 8;    // entry base, 8 entries/thread
        const float* src = feats + (size_t)(c_fbh[lvl] + e8) * 2;
        uint4 u;
        u32* up = (u32*)&u;
#pragma unroll
        for (int p = 0; p < 4; ++p) {       // 2 entries per dword
            vf4 f = *(const vf4*)(src + 4 * p);
            int w = __builtin_amdgcn_cvt_pk_fp8_f32(16.0f * f.x, 16.0f * f.y, 0, false);
            w = __builtin_amdgcn_cvt_pk_fp8_f32(16.0f * f.z, 16.0f * f.w, w, true);
            up[p] = (u32)w;
        }
        *(uint4*)(wsb + (size_t)lvl * 262144 + (size_t)e8 * 2) = u;   // 16B aligned
    } else if (b < 1346) {
        const int e = (b - 640) * 256 + tid;
        if (e < 180567) {
            if (e < 4096)       pack_lin_xy<16>(e, 0,     feats, wsb);
            else if (e < 16263) pack_lin_xy<23>(e, 4096,  feats, wsb);
            else if (e < 55567) pack_lin_xy<34>(e, 16263, feats, wsb);
            else                pack_lin_xy<50>(e, 55567, feats, wsb);
        }
    } else if (b < 1858) {
        // level 14: ns=2, gbase=0, fbase=1491287
        // gaussian0 mean = (ma.x, ma.y, mb.x); gaussian1 = (mb.y, mc.x, mc.y)
        const int e = (b - 1346) * 256 + tid;
        const float2* m2 = (const float2*)(means + (size_t)e * 6);
        const float2 ma = m2[0], mb = m2[1], mc = m2[2];
        const float2 sv = *(const float2*)(stds + 2 * e);
        const float2* f2 = (const float2*)(feats + (size_t)(1491287 + 2 * e) * 2);
        const float2 fa = f2[0], fb = f2[1];
        const float s0 = fabsf(sv.x), s1 = fabsf(sv.y);
        h8 Q0, Q1;
        Q0[0] = (_Float16)(ma.x - 0.5f); Q0[1] = (_Float16)(ma.y - 0.5f); Q0[2] = (_Float16)(mb.x - 0.5f);
        Q0[3] = (_Float16)(1.0f / (2.0f * s0 * s0 + 1e-7f));
        Q0[4] = (_Float16)(1.0f / (2.5066282746310002f * s0 + 1e-7f));
        Q0[5] = (_Float16)(1.0f / (s0 * s0));
        Q0[6] = (_Float16)fa.x; Q0[7] = (_Float16)fa.y;
        Q1[0] = (_Float16)(mb.y - 0.5f); Q1[1] = (_Float16)(mc.x - 0.5f); Q1[2] = (_Float16)(mc.y - 0.5f);
        Q1[3] = (_Float16)(1.0f / (2.0f * s1 * s1 + 1e-7f));
        Q1[4] = (_Float16)(1.0f / (2.5066282746310002f * s1 + 1e-7f));
        Q1[5] = (_Float16)(1.0f / (s1 * s1));
        Q1[6] = (_Float16)fb.x; Q1[7] = (_Float16)fb.y;
        h8* dst = (h8*)(wsb + L14_OFF) + (size_t)e * 2;
        dst[0] = Q0; dst[1] = Q1;
    } else {
        // level 15: ns=4, gbase=262144, fbase=1753431
        // means: u=(m0x,m0y,m0z,m1x) v=(m1y,m1z,m2x,m2y) w=(m2z,m3x,m3y,m3z)
        const int e = (b - 1858) * 256 + tid;
        const vf4* m4 = (const vf4*)(means + (size_t)(262144 + 4 * e) * 3);
        const vf4 u = m4[0], v = m4[1], w = m4[2];
        const vf4 s4 = *(const vf4*)(stds + 262144 + 4 * e);
        const float2* f2 = (const float2*)(feats + (size_t)(1753431 + 4 * e) * 2);
        const float2 fv[4] = {f2[0], f2[1], f2[2], f2[3]};
        const float mx[4] = {u.x, u.w, v.z, w.y};
        const float my[4] = {u.y, v.x, v.w, w.z};
        const float mz[4] = {u.z, v.y, w.x, w.w};
        const float sv[4] = {fabsf(s4.x), fabsf(s4.y), fabsf(s4.z), fabsf(s4.w)};
        h8 C0, C1, C2;
#pragma unroll
        for (int g = 0; g < 4; ++g) {
            C0[g]     = (_Float16)(mx[g] - 0.5f);
            C0[4 + g] = (_Float16)(my[g] - 0.5f);
            C1[g]     = (_Float16)(mz[g] - 0.5f);
            C1[4 + g] = (_Float16)(1.0f / (2.0f * sv[g] * sv[g] + 1e-7f));
            C2[g]     = (_Float16)fv[g].x;
            C2[4 + g] = (_Float16)fv[g].y;
        }
        unsigned char* dst = wsb + L15_OFF + (size_t)e * 48;
        *(h8*)(dst)      = C0;
        *(h8*)(dst + 16) = C1;
        *(h8*)(dst + 32) = C2;
    }
}

// grid: [0,4096) pop0 lv0-7 4thr/pt | [4096,7168) pop1 lv8-13 3thr/pt |
//       [7168,11264) L14 4thr/pt | [11264,19456) L15 8thr/pt
template<bool PACKED>
__global__ __launch_bounds__(256) void splash_enc(
    const float* __restrict__ coords, const float* __restrict__ feats,
    const float* __restrict__ means,  const float* __restrict__ stds,
    const unsigned char* __restrict__ wsb, float* __restrict__ out, int N)
{
    const int b = blockIdx.x;
    const int tid = threadIdx.x;
    const u16* ptab = (const u16*)wsb;                 // plain fp8: level L in [4,13] -> + (L-4)*131072
    float* gmm = out + (size_t)N * 32;

    if (b < 4096) {
        // ---- pop0: levels 0-7, thread q: linear level q + hashed level q+4
        const int t = b * 256 + tid;
        const int n = t >> 2, q = t & 3;
        const float cx = coords[3*n+0], cy = coords[3*n+1], cz = coords[3*n+2];
        float2 rlin, rhsh;
        if (PACKED) {
            rlin = linear_eval2_fp8(c_lres[q], c_lfb[q], cx, cy, cz, wsb);
            rhsh = plain_eval_fp8(c_h0res[q], ptab + q * 131072, cx, cy, cz);
        } else {
            rlin = linear_eval4(c_lres[q], c_lfb[q], cx, cy, cz, feats);
            rhsh = plain_eval_f32h(c_h0res[q], c_fbh[q], cx, cy, cz, feats);
        }
        *(float2*)(out + (size_t)n * 32 + 2 * q)     = rlin;
        *(float2*)(out + (size_t)n * 32 + 8 + 2 * q) = rhsh;
    } else if (b < 7168) {
        // ---- pop1: levels 8-13, thread q: levels 8+q and 11+q
        const int t = (b - 4096) * 256 + tid;               // [0, 786432)
        const int n = (int)(((unsigned long long)(unsigned)t * 0xAAAAAAABull) >> 33);
        const int q = t - 3 * n;
        const float cx = coords[3*n+0], cy = coords[3*n+1], cz = coords[3*n+2];
        float2 rA, rB;
        if (PACKED) {
            rA = plain_eval_fp8(c_p1resA[q], ptab + (4 + q) * 131072, cx, cy, cz);
            rB = plain_eval_fp8(c_p1resB[q], ptab + (7 + q) * 131072, cx, cy, cz);
        } else {
            rA = plain_eval_f32h(c_p1resA[q], c_fbh[4 + q], cx, cy, cz, feats);
            rB = plain_eval_f32h(c_p1resB[q], c_fbh[7 + q], cx, cy, cz, feats);
        }
        *(float2*)(out + (size_t)n * 32 + 16 + 2 * q) = rA;
        *(float2*)(out + (size_t)n * 32 + 22 + 2 * q) = rB;
    } else if (b < 11264) {
        // ---- L14: 4 threads/point; lane = gaussian (q&1) of corners (q>>1)+2j
        const int t = (b - 7168) * 256 + tid;
        const int n = t >> 2, q = t & 3;
        const float cx = coords[3*n+0], cy = coords[3*n+1], cz = coords[3*n+2];
        float a0, a1, ag;
        if (PACKED) {
            splash14_quarters((const h8*)(wsb + L14_OFF), q & 1, q >> 1,
                              cx, cy, cz, cx - 0.5f, cy - 0.5f, cz - 0.5f, a0, a1, ag);
        } else {
            splash_direct_part<2,2>(q * 2, 3520, 1491287, 0, cx, cy, cz,
                                    feats, means, stds, a0, a1, ag);
        }
        a0 += __shfl_xor(a0, 1); a1 += __shfl_xor(a1, 1); ag += __shfl_xor(ag, 1);
        a0 += __shfl_xor(a0, 2); a1 += __shfl_xor(a1, 2); ag += __shfl_xor(ag, 2);
        if (q == 0) {
            *(float2*)(out + (size_t)n * 32 + 28) = make_float2(a0, a1);
            gmm[2 * n] = ag;
        }
    } else {
        // ---- L15: 8 threads/point; lane = gaussian (q&3) of corners (q>>2)+2j
        const int t = (b - 11264) * 256 + tid;
        const int n = t >> 3, q = t & 7;
        const float cx = coords[3*n+0], cy = coords[3*n+1], cz = coords[3*n+2];
        float a0, a1, ag;
        if (PACKED) {
            splash15_soa(tid & 63, cx, cy, cz, cx - 0.5f, cy - 0.5f, cz - 0.5f,
                         wsb, a0, a1, ag);
        } else {
            splash_direct_part<4,1>(q, 5174, 1753431, 262144, cx, cy, cz,
                                    feats, means, stds, a0, a1, ag);
        }
        a0 += __shfl_xor(a0, 1); a1 += __shfl_xor(a1, 1); ag += __shfl_xor(ag, 1);
        a0 += __shfl_xor(a0, 2); a1 += __shfl_xor(a1, 2); ag += __shfl_xor(ag, 2);
        a0 += __shfl_xor(a0, 4); a1 += __shfl_xor(a1, 4); ag += __shfl_xor(ag, 4);
        if (q == 0) {
            *(float2*)(out + (size_t)n * 32 + 30) = make_float2(a0, a1);
            gmm[2 * n + 1] = ag;
        }
    }
}

extern "C" void kernel_launch(void* const* d_in, const int* in_sizes, int n_in,
                              void* d_out, int out_size, void* d_ws, size_t ws_size,
                              hipStream_t stream) {
    const float* coords = (const float*)d_in[0];
    const float* feats  = (const float*)d_in[1];
    const float* means  = (const float*)d_in[2];
    const float* stds   = (const float*)d_in[3];
    float* out = (float*)d_out;
    const int N = in_sizes[0] / 3;   // 262144

    const bool packed = (ws_size >= 17825792);   // need 14.7MB; keep old gate
    if (packed) {
        repack_kernel<<<2370, 256, 0, stream>>>(means, stds, feats, (unsigned char*)d_ws);
        splash_enc<true><<<19456, 256, 0, stream>>>(coords, feats, means, stds,
                                                    (const unsigned char*)d_ws, out, N);
    } else {
        splash_enc<false><<<19456, 256, 0, stream>>>(coords, feats, means, stds,
                                                     (const unsigned char*)d_ws, out, N);
    }
}

// Round 4
// 206.029 us; speedup vs baseline: 1.0524x; 1.0116x over previous
//
#include <hip/hip_runtime.h>
#include <math.h>

// SplashEncoding: 16-level hash grid, trilinear interp; levels 14/15 add
// Gaussian splash mixtures (ns=2/4) feeding both feature and GMM outputs.
//
// R12 vs R11 (main 131.4us): last overhead-free lane/request reduction.
// Four orthogonal probes have returned: bytes -50% + L3->L2 = -6% (R9),
// txns -22% = 0 (R10), lane-loads -11% (+shuffle overhead) = -1% (R11).
// Surviving model: per-lane random-gather processing ~2.1 cyc/lane/CU
// (equivalently chip-wide random line-request rate ~80 lines/cy: predicts
// 131us exactly). This round takes the one lever both models score positive
// and that adds ZERO overhead:
//  - linear levels 0-3: index is injective -> entry stores the FULL 2x2x2
//    corner cube (8 corner pairs = 16 fp8 = 16B, aligned). ONE 16B lane-load
//    replaces two 8B loads. EXACT. -4 lane-loads/pt, -4 line-requests/pt.
//    (corner_setup guarantees p <= res-2, so +1 neighbors always exist.)
// Decision rule: <=1.5% => the remaining ~148 random lane-gathers/pt are
// irreducible (hash precludes merging) -> declare roofline.

#define HMASK 131071
typedef float vf4 __attribute__((ext_vector_type(4)));
typedef float vf2 __attribute__((ext_vector_type(2)));
typedef _Float16 h8 __attribute__((ext_vector_type(8)));
typedef _Float16 h2 __attribute__((ext_vector_type(2)));
typedef unsigned short u16;
typedef unsigned int u32;

// ws byte layout:
//   [0, 2621440)            : levels 4-13 fp8 tables (131072 x 2B)
//   [2621440, 5510512)      : linear levels 0-3 cube fp8 (180567 x 16B)
//   [5767168, 9961472)      : L14 quarters (2 x 16B per slot)
//   [9961472, 16252928)     : L15 SoA slots (3 x 16B = 48B per slot)
#define LIN_OFF 2621440
#define L14_OFF 5767168
#define L15_OFF 9961472

// fbases (float2 rows) of hashed plain levels 4..13 (for repack + fallback)
__constant__ int c_fbh[10] = {180567,311639,442711,573783,704855,835927,
                              966999,1098071,1229143,1360215};
// pop0 per-q: linear levels 0..3, hashed levels 4..7
__constant__ int c_lres[4] = {16,23,34,50};
__constant__ int c_lfb[4]  = {0,4096,16263,55567};
__constant__ int c_h0res[4] = {74,109,161,237};
// pop1 per-q: levels 8+q and 11+q
__constant__ int c_p1resA[3] = {348,512,753};
__constant__ int c_p1resB[3] = {1108,1629,2394};

__device__ __forceinline__ void corner_setup(int res, float cx, float cy, float cz,
                                             int& px, int& py, int& pz,
                                             float& fx, float& fy, float& fz)
{
    const float hi = (float)res - 1.001f;            // matches jnp.clip(res*c, 0, res-1.001)
    float x = fminf(fmaxf((float)res * cx, 0.0f), hi);
    float y = fminf(fmaxf((float)res * cy, 0.0f), hi);
    float z = fminf(fmaxf((float)res * cz, 0.0f), hi);
    px = (int)x; py = (int)y; pz = (int)z;           // >=0 so trunc == floor
    fx = x - (float)px; fy = y - (float)py; fz = z - (float)pz;
}

__device__ __forceinline__ float hsel_f(u32 w, int sel) {
    h2 v;
    __builtin_memcpy(&v, &w, 4);
    return (float)v[sel];
}

// ---- fp32 fallback paths (workspace too small) --------------------------

__device__ __forceinline__ float2 linear_eval4(
    int res, int fbase, float cx, float cy, float cz,
    const float* __restrict__ feats)
{
    int px, py, pz; float fx, fy, fz;
    corner_setup(res, cx, cy, cz, px, py, pz, fx, fy, fz);
    int idxs[4]; float wyz[4];
#pragma unroll
    for (int j = 0; j < 4; ++j) {
        const int oy = (j >> 1) & 1, oz = j & 1;
        idxs[j] = px + (py + oy) * res + (pz + oz) * res * res;
        wyz[j] = (oy ? fy : 1.0f - fy) * (oz ? fz : 1.0f - fz);
    }
    vf4 fv[4];
#pragma unroll
    for (int j = 0; j < 4; ++j)
        fv[j] = *(const vf4*)(feats + (size_t)(fbase + idxs[j]) * 2);
    float a0 = 0.0f, a1 = 0.0f;
    const float gx = 1.0f - fx;
#pragma unroll
    for (int j = 0; j < 4; ++j) {
        a0 += wyz[j] * (gx * fv[j].x + fx * fv[j].z);
        a1 += wyz[j] * (gx * fv[j].y + fx * fv[j].w);
    }
    return make_float2(a0, a1);
}

__device__ __forceinline__ float2 plain_eval_f32h(
    int res, int fbase, float cx, float cy, float cz,
    const float* __restrict__ feats)
{
    int px, py, pz; float fx, fy, fz;
    corner_setup(res, cx, cy, cz, px, py, pz, fx, fy, fz);
    int   idxs[8];
    float ws[8];
#pragma unroll
    for (int k = 0; k < 8; ++k) {
        const int ox = (k >> 2) & 1, oy = (k >> 1) & 1, oz = k & 1;
        const int ix = px + ox, iy = py + oy, iz = pz + oz;
        ws[k] = (ox ? fx : 1.0f - fx) * (oy ? fy : 1.0f - fy) * (oz ? fz : 1.0f - fz);
        unsigned h = (unsigned)ix ^ ((unsigned)iy * 2654435761u) ^ ((unsigned)iz * 805459861u);
        idxs[k] = (int)(h & HMASK);
    }
    float2 fv[8];
#pragma unroll
    for (int k = 0; k < 8; ++k)
        fv[k] = *(const float2*)(feats + (size_t)(fbase + idxs[k]) * 2);
    float a0 = 0.0f, a1 = 0.0f;
#pragma unroll
    for (int k = 0; k < 8; ++k) { a0 += ws[k] * fv[k].x; a1 += ws[k] * fv[k].y; }
    return make_float2(a0, a1);
}

// ---- fp8 packed paths ----------------------------------------------------

// linear level, cube fp8 table: entry (px,py,pz) holds ALL 8 corner feature
// pairs {c000,c100,c010,c110 | c001,c101,c011,c111} as 16 fp8 = 16B aligned.
// Index injective (no hash) -> EXACT. ONE 16B load. Values 16x pre-scaled.
__device__ __forceinline__ float2 linear_eval1_fp8(
    int res, int ebase, float cx, float cy, float cz,
    const unsigned char* __restrict__ wsb)
{
    int px, py, pz; float fx, fy, fz;
    corner_setup(res, cx, cy, cz, px, py, pz, fx, fy, fz);
    const int i0 = ebase + px + py * res + pz * res * res;
    const uint4 U = *(const uint4*)(wsb + LIN_OFF + (size_t)i0 * 16);
    const float wx0 = 1.0f - fx, wy0 = 1.0f - fy;
    vf2 c00 = __builtin_amdgcn_cvt_pk_f32_fp8((int)U.x, false);
    vf2 c10 = __builtin_amdgcn_cvt_pk_f32_fp8((int)U.x, true);
    vf2 c01 = __builtin_amdgcn_cvt_pk_f32_fp8((int)U.y, false);
    vf2 c11 = __builtin_amdgcn_cvt_pk_f32_fp8((int)U.y, true);
    vf2 d00 = __builtin_amdgcn_cvt_pk_f32_fp8((int)U.z, false);
    vf2 d10 = __builtin_amdgcn_cvt_pk_f32_fp8((int)U.z, true);
    vf2 d01 = __builtin_amdgcn_cvt_pk_f32_fp8((int)U.w, false);
    vf2 d11 = __builtin_amdgcn_cvt_pk_f32_fp8((int)U.w, true);
    float s0x = wy0 * (wx0 * c00.x + fx * c10.x) + fy * (wx0 * c01.x + fx * c11.x);
    float s0y = wy0 * (wx0 * c00.y + fx * c10.y) + fy * (wx0 * c01.y + fx * c11.y);
    float s1x = wy0 * (wx0 * d00.x + fx * d10.x) + fy * (wx0 * d01.x + fx * d11.x);
    float s1y = wy0 * (wx0 * d00.y + fx * d10.y) + fy * (wx0 * d01.y + fx * d11.y);
    const float a0 = (1.0f - fz) * s0x + fz * s1x;
    const float a1 = (1.0f - fz) * s0y + fz * s1y;
    return make_float2(a0 * 0.0625f, a1 * 0.0625f);
}

// hashed plain level, fp8 table (2B/entry). Stored values are 16x.
__device__ __forceinline__ float2 plain_eval_fp8(
    int res, const u16* __restrict__ tab, float cx, float cy, float cz)
{
    int px, py, pz; float fx, fy, fz;
    corner_setup(res, cx, cy, cz, px, py, pz, fx, fy, fz);
    int   idxs[8];
    float ws[8];
#pragma unroll
    for (int k = 0; k < 8; ++k) {
        const int ox = (k >> 2) & 1, oy = (k >> 1) & 1, oz = k & 1;
        const int ix = px + ox, iy = py + oy, iz = pz + oz;
        ws[k] = (ox ? fx : 1.0f - fx) * (oy ? fy : 1.0f - fy) * (oz ? fz : 1.0f - fz);
        unsigned h = (unsigned)ix ^ ((unsigned)iy * 2654435761u) ^ ((unsigned)iz * 805459861u);
        idxs[k] = (int)(h & HMASK);
    }
    u16 v[8];
#pragma unroll
    for (int k = 0; k < 8; ++k) v[k] = tab[idxs[k]];
    float a0 = 0.0f, a1 = 0.0f;
#pragma unroll
    for (int k = 0; k < 8; ++k) {
        vf2 d = __builtin_amdgcn_cvt_pk_f32_fp8((int)v[k], false);
        a0 += ws[k] * d.x; a1 += ws[k] * d.y;
    }
    return make_float2(a0 * 0.0625f, a1 * 0.0625f);
}

// ---- splash (fp16 packed) ------------------------------------------------

__device__ __forceinline__ void gauss_pre(float w, float dx, float dy, float dz,
                                          float i2s, float inrm, float is2,
                                          float f0, float f1,
                                          float& a0, float& a1, float& ag)
{
    const float d2 = dx*dx + dy*dy + dz*dz;
    const float sq = d2 * i2s;
    const float gw = __expf(-sq) * inrm;
    const float wg = w * gw;
    a0 += wg * f0;
    a1 += wg * f1;
    ag += wg * (d2 * is2);
}

// L14: per-gaussian 16B quarter {mx-.5, my-.5, mz-.5, i2s, inrm, is2, f0, f1}.
// Lane owns gaussian g of corners (ch + 2j); adjacent lanes coalesce.
__device__ __forceinline__ void splash14_quarters(
    const h8* __restrict__ quart, int g, int ch,
    float cx, float cy, float cz, float cox, float coy, float coz,
    float& a0, float& a1, float& ag)
{
    int px, py, pz; float fx, fy, fz;
    corner_setup(3520, cx, cy, cz, px, py, pz, fx, fy, fz);
    a0 = 0.0f; a1 = 0.0f; ag = 0.0f;
#pragma unroll
    for (int j = 0; j < 4; ++j) {
        const int k = ch + 2 * j;
        const int ox = (k >> 2) & 1, oy = (k >> 1) & 1, oz = k & 1;
        const int ix = px + ox, iy = py + oy, iz = pz + oz;
        const float w = (ox ? fx : 1.0f - fx) * (oy ? fy : 1.0f - fy) * (oz ? fz : 1.0f - fz);
        unsigned h = (unsigned)ix ^ ((unsigned)iy * 2654435761u) ^ ((unsigned)iz * 805459861u);
        const int idx = (int)(h & HMASK);
        h8 Q = quart[(size_t)idx * 2 + g];
        gauss_pre(w, cox - (float)Q[0], coy - (float)Q[1], coz - (float)Q[2],
                  (float)Q[3], (float)Q[4], (float)Q[5], (float)Q[6], (float)Q[7],
                  a0, a1, ag);
    }
}

// L15: 48B SoA slot = chunk0 {mx[0..3],my[0..3]}, chunk1 {mz[0..3],i2s[0..3]},
// chunk2 {f0[0..3],f1[0..3]}. Quad lanes g=0..2 load chunk g (lane 3 loads
// nothing); redistribution via __shfl on the DS pipe. inrm/is2 derived from
// i2s (is2 = 2*i2s, inrm = sqrt(i2s/pi); rel err ~3e-6 vs stored).
__device__ __forceinline__ void splash15_soa(
    int lane, float cx, float cy, float cz, float cox, float coy, float coz,
    const unsigned char* __restrict__ wsb, float& a0, float& a1, float& ag)
{
    int px, py, pz; float fx, fy, fz;
    corner_setup(5174, cx, cy, cz, px, py, pz, fx, fy, fz);
    a0 = 0.0f; a1 = 0.0f; ag = 0.0f;
    const int q  = lane & 7;
    const int ch = q >> 2, g = q & 3;
    const int B  = lane & ~3;
    const int hdw = g >> 1;     // which dword of the half-pair
    const int hsel = g & 1;     // which half within the dword
#pragma unroll
    for (int j = 0; j < 4; ++j) {
        const int k = ch + 2 * j;
        const int ox = (k >> 2) & 1, oy = (k >> 1) & 1, oz = k & 1;
        const int ix = px + ox, iy = py + oy, iz = pz + oz;
        const float w = (ox ? fx : 1.0f - fx) * (oy ? fy : 1.0f - fy) * (oz ? fz : 1.0f - fz);
        unsigned h = (unsigned)ix ^ ((unsigned)iy * 2654435761u) ^ ((unsigned)iz * 805459861u);
        const int idx = (int)(h & HMASK);
        uint4 ck = make_uint4(0u, 0u, 0u, 0u);
        if (g < 3)
            ck = *(const uint4*)(wsb + L15_OFF + (size_t)idx * 48 + (size_t)g * 16);
        // pull all 4 dwords of each source lane's chunk
        const u32 x01 = (u32)__shfl((int)ck.x, B,     64);
        const u32 x23 = (u32)__shfl((int)ck.y, B,     64);
        const u32 y01 = (u32)__shfl((int)ck.z, B,     64);
        const u32 y23 = (u32)__shfl((int)ck.w, B,     64);
        const u32 z01 = (u32)__shfl((int)ck.x, B + 1, 64);
        const u32 z23 = (u32)__shfl((int)ck.y, B + 1, 64);
        const u32 s01 = (u32)__shfl((int)ck.z, B + 1, 64);
        const u32 s23 = (u32)__shfl((int)ck.w, B + 1, 64);
        const u32 f001 = (u32)__shfl((int)ck.x, B + 2, 64);
        const u32 f023 = (u32)__shfl((int)ck.y, B + 2, 64);
        const u32 f101 = (u32)__shfl((int)ck.z, B + 2, 64);
        const u32 f123 = (u32)__shfl((int)ck.w, B + 2, 64);
        const float mx  = hsel_f(hdw ? x23 : x01, hsel);
        const float my  = hsel_f(hdw ? y23 : y01, hsel);
        const float mz  = hsel_f(hdw ? z23 : z01, hsel);
        const float i2s = hsel_f(hdw ? s23 : s01, hsel);
        const float f0  = hsel_f(hdw ? f023 : f001, hsel);
        const float f1  = hsel_f(hdw ? f123 : f101, hsel);
        const float inrm = __fsqrt_rn(i2s * 0.31830988618f);   // sqrt(i2s/pi)
        const float is2  = 2.0f * i2s;
        gauss_pre(w, cox - mx, coy - my, coz - mz, i2s, inrm, is2, f0, f1, a0, a1, ag);
    }
}

// fallback splash (direct fp32 table loads), corner range [k0, k0+KN)
template<int NS, int KN>
__device__ __forceinline__ void splash_direct_part(
    int k0, int res, int fbase, int gbase, float cx, float cy, float cz,
    const float* __restrict__ feats, const float* __restrict__ means,
    const float* __restrict__ stds, float& a0, float& a1, float& ag)
{
    int px, py, pz; float fx, fy, fz;
    corner_setup(res, cx, cy, cz, px, py, pz, fx, fy, fz);
    a0 = 0.0f; a1 = 0.0f; ag = 0.0f;
#pragma unroll
    for (int kk = 0; kk < KN; ++kk) {
        const int k = k0 + kk;
        const int ox = (k >> 2) & 1, oy = (k >> 1) & 1, oz = k & 1;
        const int ix = px + ox, iy = py + oy, iz = pz + oz;
        const float w = (ox ? fx : 1.0f - fx) * (oy ? fy : 1.0f - fy) * (oz ? fz : 1.0f - fz);
        unsigned h = (unsigned)ix ^ ((unsigned)iy * 2654435761u) ^ ((unsigned)iz * 805459861u);
        const int idx = (int)(h & HMASK);
        const int grow = gbase + idx * NS;
        const float* m = means + (size_t)grow * 3;
        const float* s = stds + grow;
        const float* f = feats + (size_t)(fbase + idx * NS) * 2;
#pragma unroll
        for (int si = 0; si < NS; ++si) {
            const float dx = cx - m[3*si], dy = cy - m[3*si+1], dz = cz - m[3*si+2];
            const float sva = fabsf(s[si]);
            const float d2 = dx*dx + dy*dy + dz*dz;
            const float s2 = sva * sva;
            const float sq = d2 / (2.0f * s2 + 1e-7f);
            const float gw = expf(-sq) / (2.5066282746310002f * sva + 1e-7f);
            const float wg = w * gw;
            a0 += wg * f[2*si];
            a1 += wg * f[2*si+1];
            ag += wg * (d2 / s2);
        }
    }
}

// ---- repack --------------------------------------------------------------

// Cube pack: entry e (base corner) stores all 8 corner feature pairs as fp8.
// corner_setup guarantees base p <= res-2, so +1 reads below are the real
// corners for every queried base; entries with p=res-1 are never queried
// (their neighbor reads stay inside feats -> harmless garbage).
__device__ __forceinline__ void pack_lin_cube(
    int e, int res, const float* __restrict__ feats, unsigned char* __restrict__ wsb)
{
    const int r2 = res * res;
    const float2 f000 = *(const float2*)(feats + 2 * (size_t)e);
    const float2 f100 = *(const float2*)(feats + 2 * (size_t)(e + 1));
    const float2 f010 = *(const float2*)(feats + 2 * (size_t)(e + res));
    const float2 f110 = *(const float2*)(feats + 2 * (size_t)(e + res + 1));
    const float2 f001 = *(const float2*)(feats + 2 * (size_t)(e + r2));
    const float2 f101 = *(const float2*)(feats + 2 * (size_t)(e + r2 + 1));
    const float2 f011 = *(const float2*)(feats + 2 * (size_t)(e + r2 + res));
    const float2 f111 = *(const float2*)(feats + 2 * (size_t)(e + r2 + res + 1));
    int w0 = __builtin_amdgcn_cvt_pk_fp8_f32(16.0f * f000.x, 16.0f * f000.y, 0, false);
    w0 = __builtin_amdgcn_cvt_pk_fp8_f32(16.0f * f100.x, 16.0f * f100.y, w0, true);
    int w1 = __builtin_amdgcn_cvt_pk_fp8_f32(16.0f * f010.x, 16.0f * f010.y, 0, false);
    w1 = __builtin_amdgcn_cvt_pk_fp8_f32(16.0f * f110.x, 16.0f * f110.y, w1, true);
    int w2 = __builtin_amdgcn_cvt_pk_fp8_f32(16.0f * f001.x, 16.0f * f001.y, 0, false);
    w2 = __builtin_amdgcn_cvt_pk_fp8_f32(16.0f * f101.x, 16.0f * f101.y, w2, true);
    int w3 = __builtin_amdgcn_cvt_pk_fp8_f32(16.0f * f011.x, 16.0f * f011.y, 0, false);
    w3 = __builtin_amdgcn_cvt_pk_fp8_f32(16.0f * f111.x, 16.0f * f111.y, w3, true);
    *(uint4*)(wsb + LIN_OFF + (size_t)e * 16) = make_uint4((u32)w0, (u32)w1, (u32)w2, (u32)w3);
}

// repack threads (by block range):
//   [0,640)     plain levels 4-13 -> fp8, 8 entries/thread
//   [640,1346)  linear cube table, 1 entry/thread (180567 entries)
//   [1346,1858) L14 slots (131072) -> 2 per-gaussian quarters
//   [1858,2370) L15 slots (131072) -> 3-chunk SoA (48B)
__global__ __launch_bounds__(256) void repack_kernel(
    const float* __restrict__ means, const float* __restrict__ stds,
    const float* __restrict__ feats, unsigned char* __restrict__ wsb)
{
    const int b = blockIdx.x;
    const int tid = threadIdx.x;
    if (b < 640) {
        const int j   = b * 256 + tid;      // 0..163839
        const int lvl = j >> 14;            // /16384
        const int e8  = (j & 16383) * 8;    // entry base, 8 entries/thread
        const float* src = feats + (size_t)(c_fbh[lvl] + e8) * 2;
        uint4 u;
        u32* up = (u32*)&u;
#pragma unroll
        for (int p = 0; p < 4; ++p) {       // 2 entries per dword
            vf4 f = *(const vf4*)(src + 4 * p);
            int w = __builtin_amdgcn_cvt_pk_fp8_f32(16.0f * f.x, 16.0f * f.y, 0, false);
            w = __builtin_amdgcn_cvt_pk_fp8_f32(16.0f * f.z, 16.0f * f.w, w, true);
            up[p] = (u32)w;
        }
        *(uint4*)(wsb + (size_t)lvl * 262144 + (size_t)e8 * 2) = u;   // 16B aligned
    } else if (b < 1346) {
        const int e = (b - 640) * 256 + tid;
        if (e < 180567) {
            if (e < 4096)       pack_lin_cube(e, 16, feats, wsb);
            else if (e < 16263) pack_lin_cube(e, 23, feats, wsb);
            else if (e < 55567) pack_lin_cube(e, 34, feats, wsb);
            else                pack_lin_cube(e, 50, feats, wsb);
        }
    } else if (b < 1858) {
        // level 14: ns=2, gbase=0, fbase=1491287
        // gaussian0 mean = (ma.x, ma.y, mb.x); gaussian1 = (mb.y, mc.x, mc.y)
        const int e = (b - 1346) * 256 + tid;
        const float2* m2 = (const float2*)(means + (size_t)e * 6);
        const float2 ma = m2[0], mb = m2[1], mc = m2[2];
        const float2 sv = *(const float2*)(stds + 2 * e);
        const float2* f2 = (const float2*)(feats + (size_t)(1491287 + 2 * e) * 2);
        const float2 fa = f2[0], fb = f2[1];
        const float s0 = fabsf(sv.x), s1 = fabsf(sv.y);
        h8 Q0, Q1;
        Q0[0] = (_Float16)(ma.x - 0.5f); Q0[1] = (_Float16)(ma.y - 0.5f); Q0[2] = (_Float16)(mb.x - 0.5f);
        Q0[3] = (_Float16)(1.0f / (2.0f * s0 * s0 + 1e-7f));
        Q0[4] = (_Float16)(1.0f / (2.5066282746310002f * s0 + 1e-7f));
        Q0[5] = (_Float16)(1.0f / (s0 * s0));
        Q0[6] = (_Float16)fa.x; Q0[7] = (_Float16)fa.y;
        Q1[0] = (_Float16)(mb.y - 0.5f); Q1[1] = (_Float16)(mc.x - 0.5f); Q1[2] = (_Float16)(mc.y - 0.5f);
        Q1[3] = (_Float16)(1.0f / (2.0f * s1 * s1 + 1e-7f));
        Q1[4] = (_Float16)(1.0f / (2.5066282746310002f * s1 + 1e-7f));
        Q1[5] = (_Float16)(1.0f / (s1 * s1));
        Q1[6] = (_Float16)fb.x; Q1[7] = (_Float16)fb.y;
        h8* dst = (h8*)(wsb + L14_OFF) + (size_t)e * 2;
        dst[0] = Q0; dst[1] = Q1;
    } else {
        // level 15: ns=4, gbase=262144, fbase=1753431
        // means: u=(m0x,m0y,m0z,m1x) v=(m1y,m1z,m2x,m2y) w=(m2z,m3x,m3y,m3z)
        const int e = (b - 1858) * 256 + tid;
        const vf4* m4 = (const vf4*)(means + (size_t)(262144 + 4 * e) * 3);
        const vf4 u = m4[0], v = m4[1], w = m4[2];
        const vf4 s4 = *(const vf4*)(stds + 262144 + 4 * e);
        const float2* f2 = (const float2*)(feats + (size_t)(1753431 + 4 * e) * 2);
        const float2 fv[4] = {f2[0], f2[1], f2[2], f2[3]};
        const float mx[4] = {u.x, u.w, v.z, w.y};
        const float my[4] = {u.y, v.x, v.w, w.z};
        const float mz[4] = {u.z, v.y, w.x, w.w};
        const float sv[4] = {fabsf(s4.x), fabsf(s4.y), fabsf(s4.z), fabsf(s4.w)};
        h8 C0, C1, C2;
#pragma unroll
        for (int g = 0; g < 4; ++g) {
            C0[g]     = (_Float16)(mx[g] - 0.5f);
            C0[4 + g] = (_Float16)(my[g] - 0.5f);
            C1[g]     = (_Float16)(mz[g] - 0.5f);
            C1[4 + g] = (_Float16)(1.0f / (2.0f * sv[g] * sv[g] + 1e-7f));
            C2[g]     = (_Float16)fv[g].x;
            C2[4 + g] = (_Float16)fv[g].y;
        }
        unsigned char* dst = wsb + L15_OFF + (size_t)e * 48;
        *(h8*)(dst)      = C0;
        *(h8*)(dst + 16) = C1;
        *(h8*)(dst + 32) = C2;
    }
}

// grid: [0,4096) pop0 lv0-7 4thr/pt | [4096,7168) pop1 lv8-13 3thr/pt |
//       [7168,11264) L14 4thr/pt | [11264,19456) L15 8thr/pt
template<bool PACKED>
__global__ __launch_bounds__(256) void splash_enc(
    const float* __restrict__ coords, const float* __restrict__ feats,
    const float* __restrict__ means,  const float* __restrict__ stds,
    const unsigned char* __restrict__ wsb, float* __restrict__ out, int N)
{
    const int b = blockIdx.x;
    const int tid = threadIdx.x;
    const u16* ptab = (const u16*)wsb;                 // plain fp8: level L in [4,13] -> + (L-4)*131072
    float* gmm = out + (size_t)N * 32;

    if (b < 4096) {
        // ---- pop0: levels 0-7, thread q: linear level q + hashed level q+4
        const int t = b * 256 + tid;
        const int n = t >> 2, q = t & 3;
        const float cx = coords[3*n+0], cy = coords[3*n+1], cz = coords[3*n+2];
        float2 rlin, rhsh;
        if (PACKED) {
            rlin = linear_eval1_fp8(c_lres[q], c_lfb[q], cx, cy, cz, wsb);
            rhsh = plain_eval_fp8(c_h0res[q], ptab + q * 131072, cx, cy, cz);
        } else {
            rlin = linear_eval4(c_lres[q], c_lfb[q], cx, cy, cz, feats);
            rhsh = plain_eval_f32h(c_h0res[q], c_fbh[q], cx, cy, cz, feats);
        }
        *(float2*)(out + (size_t)n * 32 + 2 * q)     = rlin;
        *(float2*)(out + (size_t)n * 32 + 8 + 2 * q) = rhsh;
    } else if (b < 7168) {
        // ---- pop1: levels 8-13, thread q: levels 8+q and 11+q
        const int t = (b - 4096) * 256 + tid;               // [0, 786432)
        const int n = (int)(((unsigned long long)(unsigned)t * 0xAAAAAAABull) >> 33);
        const int q = t - 3 * n;
        const float cx = coords[3*n+0], cy = coords[3*n+1], cz = coords[3*n+2];
        float2 rA, rB;
        if (PACKED) {
            rA = plain_eval_fp8(c_p1resA[q], ptab + (4 + q) * 131072, cx, cy, cz);
            rB = plain_eval_fp8(c_p1resB[q], ptab + (7 + q) * 131072, cx, cy, cz);
        } else {
            rA = plain_eval_f32h(c_p1resA[q], c_fbh[4 + q], cx, cy, cz, feats);
            rB = plain_eval_f32h(c_p1resB[q], c_fbh[7 + q], cx, cy, cz, feats);
        }
        *(float2*)(out + (size_t)n * 32 + 16 + 2 * q) = rA;
        *(float2*)(out + (size_t)n * 32 + 22 + 2 * q) = rB;
    } else if (b < 11264) {
        // ---- L14: 4 threads/point; lane = gaussian (q&1) of corners (q>>1)+2j
        const int t = (b - 7168) * 256 + tid;
        const int n = t >> 2, q = t & 3;
        const float cx = coords[3*n+0], cy = coords[3*n+1], cz = coords[3*n+2];
        float a0, a1, ag;
        if (PACKED) {
            splash14_quarters((const h8*)(wsb + L14_OFF), q & 1, q >> 1,
                              cx, cy, cz, cx - 0.5f, cy - 0.5f, cz - 0.5f, a0, a1, ag);
        } else {
            splash_direct_part<2,2>(q * 2, 3520, 1491287, 0, cx, cy, cz,
                                    feats, means, stds, a0, a1, ag);
        }
        a0 += __shfl_xor(a0, 1); a1 += __shfl_xor(a1, 1); ag += __shfl_xor(ag, 1);
        a0 += __shfl_xor(a0, 2); a1 += __shfl_xor(a1, 2); ag += __shfl_xor(ag, 2);
        if (q == 0) {
            *(float2*)(out + (size_t)n * 32 + 28) = make_float2(a0, a1);
            gmm[2 * n] = ag;
        }
    } else {
        // ---- L15: 8 threads/point; lane = gaussian (q&3) of corners (q>>2)+2j
        const int t = (b - 11264) * 256 + tid;
        const int n = t >> 3, q = t & 7;
        const float cx = coords[3*n+0], cy = coords[3*n+1], cz = coords[3*n+2];
        float a0, a1, ag;
        if (PACKED) {
            splash15_soa(tid & 63, cx, cy, cz, cx - 0.5f, cy - 0.5f, cz - 0.5f,
                         wsb, a0, a1, ag);
        } else {
            splash_direct_part<4,1>(q, 5174, 1753431, 262144, cx, cy, cz,
                                    feats, means, stds, a0, a1, ag);
        }
        a0 += __shfl_xor(a0, 1); a1 += __shfl_xor(a1, 1); ag += __shfl_xor(ag, 1);
        a0 += __shfl_xor(a0, 2); a1 += __shfl_xor(a1, 2); ag += __shfl_xor(ag, 2);
        a0 += __shfl_xor(a0, 4); a1 += __shfl_xor(a1, 4); ag += __shfl_xor(ag, 4);
        if (q == 0) {
            *(float2*)(out + (size_t)n * 32 + 30) = make_float2(a0, a1);
            gmm[2 * n + 1] = ag;
        }
    }
}

extern "C" void kernel_launch(void* const* d_in, const int* in_sizes, int n_in,
                              void* d_out, int out_size, void* d_ws, size_t ws_size,
                              hipStream_t stream) {
    const float* coords = (const float*)d_in[0];
    const float* feats  = (const float*)d_in[1];
    const float* means  = (const float*)d_in[2];
    const float* stds   = (const float*)d_in[3];
    float* out = (float*)d_out;
    const int N = in_sizes[0] / 3;   // 262144

    const bool packed = (ws_size >= 17825792);   // need 15.5MB; keep old gate
    if (packed) {
        repack_kernel<<<2370, 256, 0, stream>>>(means, stds, feats, (unsigned char*)d_ws);
        splash_enc<true><<<19456, 256, 0, stream>>>(coords, feats, means, stds,
                                                    (const unsigned char*)d_ws, out, N);
    } else {
        splash_enc<false><<<19456, 256, 0, stream>>>(coords, feats, means, stds,
                                                     (const unsigned char*)d_ws, out, N);
    }
}